// Round 2
// baseline (13138.708 us; speedup 1.0000x reference)
//
#include <hip/hip_runtime.h>

// GRU scan, 2 layers, B=64 T=4096 D=H=128 — skewed-layer pipeline.
// 4 persistent WGs x 16 batch rows x 512 threads (8 waves).
// Weights stationary in VGPR/AGPR as mfma_f32_16x16x32_bf16 B-frags.
// Layer 1 runs one timestep behind layer 0 so every barrier phase has
// 24 MFMAs + one gate-set of VALU with NO intra-phase dependency:
//   Phase A(t): MFMA layer0(t)  || gate-VALU h1(t-2) (from C accs)
//   Phase B(t): MFMA layer1(t-1)|| gate-VALU h0(t)   (from A accs)
// LDS uses fragment-linear layout: reading lane i reads bytes 16*i of its
// block (m97 contiguous pattern, conflict-free); writers scatter b16.

#define Bsz  64
#define Tlen 4096
#define Din  128
#define Hd   128

typedef __attribute__((ext_vector_type(8))) short short8;     // 8 bf16
typedef __attribute__((ext_vector_type(4))) short short4v;    // 4 bf16
typedef __attribute__((ext_vector_type(4))) float float4v;
typedef __attribute__((ext_vector_type(2))) unsigned int uintx2;

#define MFMA16(a, b, c) __builtin_amdgcn_mfma_f32_16x16x32_bf16((a), (b), (c), 0, 0, 0)

static __device__ __forceinline__ float fast_exp2(float x) {
#if __has_builtin(__builtin_amdgcn_exp2f)
  return __builtin_amdgcn_exp2f(x);
#else
  return exp2f(x);
#endif
}
static __device__ __forceinline__ float fast_rcp(float x) {
  return __builtin_amdgcn_rcpf(x);
}
static __device__ __forceinline__ short f2bf(float f) {  // RTNE fp32->bf16
  unsigned u = __builtin_bit_cast(unsigned, f);
  u = (u + 0x7FFFu + ((u >> 16) & 1u)) >> 16;
  return (short)u;
}
static __device__ __forceinline__ unsigned pk2bf(float a, float b) {  // lo=a hi=b
#if __has_builtin(__builtin_amdgcn_cvt_pk_bf16_f32)
  auto v = __builtin_amdgcn_cvt_pk_bf16_f32(a, b);
  return __builtin_bit_cast(unsigned, v);
#else
  return (unsigned)(unsigned short)f2bf(a) | ((unsigned)(unsigned short)f2bf(b) << 16);
#endif
}
static __device__ __forceinline__ short8 loadw8(const float* __restrict__ p) {
  short8 r;
  #pragma unroll
  for (int j = 0; j < 8; ++j) r[j] = f2bf(p[j]);
  return r;
}

// LDS blocks (shorts), each block = 4 ksteps x 64 lanes x 8 shorts = 2048:
//   X: [0,2048)   H0 buf b: [2048+2048b, ...)   H1 buf b: [6144+2048b, ...)
// Frag layout inside a block: addr = s*512 + quad*128 + row*8 + j
//   == reading lane (quad*16+lc) reads 16B at lane*16 for kstep s.

__global__ __launch_bounds__(512, 2) void gru_scan(
    const float* __restrict__ x,
    const float* __restrict__ Wih0, const float* __restrict__ Whh0,
    const float* __restrict__ bih0, const float* __restrict__ bhh0,
    const float* __restrict__ Wih1, const float* __restrict__ Whh1,
    const float* __restrict__ bih1, const float* __restrict__ bhh1,
    float* __restrict__ out) {
  __shared__ alignas(16) short Abuf[10240];

  const int tid   = threadIdx.x;
  const int wave  = tid >> 6;
  const int lane  = tid & 63;
  const int lc    = lane & 15;
  const int quad  = lane >> 4;
  const int q8    = quad * 8;
  const int lane8 = lane * 8;
  const int bbase = blockIdx.x * 16;

  // ---- stationary weight fragments (B-operand) ---------------------------
  const int nr = wave * 16 + lc;
  const int nz = 128 + wave * 16 + lc;
  const int nn = 256 + wave * 16 + lc;

  short8 fr0[8], fz0[8], fin0[4], fhn0[4];
  short8 fr1[8], fz1[8], fin1[4], fhn1[4];
  #pragma unroll
  for (int s = 0; s < 4; ++s) {
    const int k = 32 * s + q8;
    fr0[s]     = loadw8(Wih0 + nr * Din + k);
    fz0[s]     = loadw8(Wih0 + nz * Din + k);
    fin0[s]    = loadw8(Wih0 + nn * Din + k);
    fr0[s + 4] = loadw8(Whh0 + nr * Hd + k);
    fz0[s + 4] = loadw8(Whh0 + nz * Hd + k);
    fhn0[s]    = loadw8(Whh0 + nn * Hd + k);
    fr1[s]     = loadw8(Wih1 + nr * Hd + k);
    fz1[s]     = loadw8(Wih1 + nz * Hd + k);
    fin1[s]    = loadw8(Wih1 + nn * Hd + k);
    fr1[s + 4] = loadw8(Whh1 + nr * Hd + k);
    fz1[s + 4] = loadw8(Whh1 + nz * Hd + k);
    fhn1[s]    = loadw8(Whh1 + nn * Hd + k);
  }

  // gate constants, exp2-domain (biases folded into the fma constant)
  const float nL  = -1.44269504088896f;   // -log2(e)
  const float n2L = -2.88539008177793f;   // -2*log2(e)
  const float kr0 = nL * (bih0[nr] + bhh0[nr]);
  const float kz0 = nL * (bih0[nz] + bhh0[nz]);
  const float ki0 = n2L * bih0[nn];
  const float kh0 = n2L * bhh0[nn];
  const float kr1 = nL * (bih1[nr] + bhh1[nr]);
  const float kz1 = nL * (bih1[nz] + bhh1[nz]);
  const float ki1 = n2L * bih1[nn];
  const float kh1 = n2L * bhh1[nn];

  // h-write base in frag layout: element (row, col): col=wave*16+lc
  const int col    = wave * 16 + lc;
  const int hwbase = ((col >> 5) << 9) + (((col >> 3) & 3) << 7) + (col & 7);

  // x staging: thread writes its 4-short slot at 4*tid (contiguous b64)
  const int xrow = (tid >> 1) & 15;
  const int xcol = ((tid >> 7) << 5) + (((tid >> 5) & 3) << 3) + ((tid & 1) << 2);
  const float* xg = x + (size_t)(bbase + xrow) * (Tlen * Din) + xcol;
  const int xw = 4 * tid;

  // ---- prologue: zero H regions, stage x_0 -------------------------------
  {
    int* zb = (int*)Abuf;
    #pragma unroll
    for (int i = 0; i < 8; ++i) zb[1024 + tid + 512 * i] = 0;
    const float4v v0 = *(const float4v*)(xg);
    const unsigned p0 = pk2bf(v0[0], v0[1]);
    const unsigned p1 = pk2bf(v0[2], v0[3]);
    uintx2 pp = {p0, p1};
    *(short4v*)&Abuf[xw] = __builtin_bit_cast(short4v, pp);
  }
  __syncthreads();

  const float4v Z4 = {0.f, 0.f, 0.f, 0.f};
  float4v Ar = Z4, Az = Z4, Ain = Z4, Ahn = Z4;   // layer0 accs (step t)
  float4v Cr = Z4, Cz = Z4, Cin = Z4, Chn = Z4;   // layer1 accs (step t-1)
  float h0p[4] = {0.f, 0.f, 0.f, 0.f};
  float h1p[4] = {0.f, 0.f, 0.f, 0.f};
  float4v xv;
  int t;

#define GATE(acc_r, acc_z, acc_in, acc_hn, KR, KZ, KI, KH, hp, dst, S)        \
  {                                                                           \
    const float er = fast_exp2(fmaf((acc_r)[S], nL, (KR)));                   \
    const float rr = fast_rcp(1.0f + er);                                     \
    const float ez = fast_exp2(fmaf((acc_z)[S], nL, (KZ)));                   \
    const float zz = fast_rcp(1.0f + ez);                                     \
    float vv = fmaf(rr, fmaf((acc_hn)[S], n2L, (KH)),                         \
                    fmaf((acc_in)[S], n2L, (KI)));                            \
    vv = fminf(vv, 126.0f);                                                   \
    const float e2 = fast_exp2(vv);                                           \
    const float nn_ = (1.0f - e2) * fast_rcp(1.0f + e2);                      \
    (dst)[S] = fmaf(zz, (hp)[S] - nn_, nn_);                                  \
    (hp)[S] = (dst)[S];                                                       \
  }

  // Phase A(t): MFMA layer0(t) [X + H0 buf P^1] || V1(t-2) -> H1 buf P
#define PH_A(P, DOV1)                                                         \
  {                                                                           \
    const int tn = (t + 1 < Tlen) ? (t + 1) : (Tlen - 1);                     \
    xv = *(const float4v*)(xg + (size_t)tn * Din);                            \
    Ar = Z4; Az = Z4; Ain = Z4; Ahn = Z4;                                     \
    float h1n[4];                                                             \
    _Pragma("unroll")                                                         \
    for (int s = 0; s < 4; ++s) {                                             \
      const short8 a = *(const short8*)&Abuf[s * 512 + lane8];                \
      Ar  = MFMA16(a, fr0[s], Ar);                                            \
      Az  = MFMA16(a, fz0[s], Az);                                            \
      Ain = MFMA16(a, fin0[s], Ain);                                          \
      if (DOV1) GATE(Cr, Cz, Cin, Chn, kr1, kz1, ki1, kh1, h1p, h1n, s)       \
    }                                                                         \
    _Pragma("unroll")                                                         \
    for (int s = 0; s < 4; ++s) {                                             \
      const short8 a =                                                        \
          *(const short8*)&Abuf[2048 + ((P) ^ 1) * 2048 + s * 512 + lane8];   \
      Ar  = MFMA16(a, fr0[4 + s], Ar);                                        \
      Az  = MFMA16(a, fz0[4 + s], Az);                                        \
      Ahn = MFMA16(a, fhn0[s], Ahn);                                          \
      if ((DOV1) && (s & 1)) {                                                \
        const unsigned pk = pk2bf(h1n[s - 1], h1n[s]);                        \
        Abuf[6144 + (P) * 2048 + hwbase + (quad * 4 + s - 1) * 8] =           \
            (short)pk;                                                        \
        Abuf[6144 + (P) * 2048 + hwbase + (quad * 4 + s) * 8] =               \
            (short)(pk >> 16);                                                \
      }                                                                       \
    }                                                                         \
  }                                                                           \
  __syncthreads();

  // Phase B(t): MFMA layer1(t-1) [H0 buf P^1 + H1 buf P] || V0(t) -> H0 buf P
#define PH_B(P, DOC)                                                          \
  {                                                                           \
    float h0n[4];                                                             \
    if (DOC) { Cr = Z4; Cz = Z4; Cin = Z4; Chn = Z4; }                        \
    _Pragma("unroll")                                                         \
    for (int s = 0; s < 4; ++s) {                                             \
      if (DOC) {                                                              \
        const short8 a =                                                      \
            *(const short8*)&Abuf[2048 + ((P) ^ 1) * 2048 + s * 512 + lane8]; \
        Cr  = MFMA16(a, fr1[s], Cr);                                          \
        Cz  = MFMA16(a, fz1[s], Cz);                                          \
        Cin = MFMA16(a, fin1[s], Cin);                                        \
      }                                                                       \
      GATE(Ar, Az, Ain, Ahn, kr0, kz0, ki0, kh0, h0p, h0n, s)                 \
    }                                                                         \
    _Pragma("unroll")                                                         \
    for (int s = 0; s < 4; ++s) {                                             \
      if (DOC) {                                                              \
        const short8 a =                                                      \
            *(const short8*)&Abuf[6144 + (P) * 2048 + s * 512 + lane8];       \
        Cr  = MFMA16(a, fr1[4 + s], Cr);                                      \
        Cz  = MFMA16(a, fz1[4 + s], Cz);                                      \
        Chn = MFMA16(a, fhn1[s], Chn);                                        \
      }                                                                       \
      if (s & 1) {                                                            \
        const unsigned pk = pk2bf(h0n[s - 1], h0n[s]);                        \
        Abuf[2048 + (P) * 2048 + hwbase + (quad * 4 + s - 1) * 8] =           \
            (short)pk;                                                        \
        Abuf[2048 + (P) * 2048 + hwbase + (quad * 4 + s) * 8] =               \
            (short)(pk >> 16);                                                \
      }                                                                       \
    }                                                                         \
    {                                                                         \
      const unsigned p0 = pk2bf(xv[0], xv[1]);                                \
      const unsigned p1 = pk2bf(xv[2], xv[3]);                                \
      uintx2 pp = {p0, p1};                                                   \
      *(short4v*)&Abuf[xw] = __builtin_bit_cast(short4v, pp);                 \
    }                                                                         \
  }                                                                           \
  __syncthreads();

  // ---- pipeline ----------------------------------------------------------
  t = 0; PH_A(0, 0) PH_B(0, 0)          // V1 invalid, C accs invalid: skip
  t = 1; PH_A(1, 0) PH_B(1, 1)          // first valid C accs (layer1 step 0)
  for (int tt = 2; tt < Tlen; tt += 2) {
    t = tt;     PH_A(0, 1) PH_B(0, 1)
    t = tt + 1; PH_A(1, 1) PH_B(1, 1)
  }

  // ---- epilogue: finish layer1 steps T-2 and T-1 -------------------------
  {  // phase A(T): V1(T-2), write h1(T-2) -> H1 buf (T&1)=0
    float h1n[4];
    #pragma unroll
    for (int s = 0; s < 4; ++s) GATE(Cr, Cz, Cin, Chn, kr1, kz1, ki1, kh1, h1p, h1n, s)
    #pragma unroll
    for (int s = 1; s < 4; s += 2) {
      const unsigned pk = pk2bf(h1n[s - 1], h1n[s]);
      Abuf[6144 + hwbase + (quad * 4 + s - 1) * 8] = (short)pk;
      Abuf[6144 + hwbase + (quad * 4 + s) * 8]     = (short)(pk >> 16);
    }
  }
  __syncthreads();
  {  // phase B(T): MFMA layer1(T-1): H0 buf 1, H1 buf 0; then V1(T-1)
    Cr = Z4; Cz = Z4; Cin = Z4; Chn = Z4;
    #pragma unroll
    for (int s = 0; s < 4; ++s) {
      const short8 a = *(const short8*)&Abuf[4096 + s * 512 + lane8];
      Cr  = MFMA16(a, fr1[s], Cr);
      Cz  = MFMA16(a, fz1[s], Cz);
      Cin = MFMA16(a, fin1[s], Cin);
    }
    #pragma unroll
    for (int s = 0; s < 4; ++s) {
      const short8 a = *(const short8*)&Abuf[6144 + s * 512 + lane8];
      Cr  = MFMA16(a, fr1[4 + s], Cr);
      Cz  = MFMA16(a, fz1[4 + s], Cz);
      Chn = MFMA16(a, fhn1[s], Chn);
    }
    float h1n[4];
    #pragma unroll
    for (int s = 0; s < 4; ++s) GATE(Cr, Cz, Cin, Chn, kr1, kz1, ki1, kh1, h1p, h1n, s)
  }

  // ---- output ------------------------------------------------------------
  #pragma unroll
  for (int i = 0; i < 4; ++i) {
    const int b = bbase + quad * 4 + i;
    out[b * Hd + col]            = h0p[i];
    out[Bsz * Hd + b * Hd + col] = h1p[i];
  }
}

extern "C" void kernel_launch(void* const* d_in, const int* in_sizes, int n_in,
                              void* d_out, int out_size, void* d_ws, size_t ws_size,
                              hipStream_t stream) {
  (void)in_sizes; (void)n_in; (void)out_size; (void)d_ws; (void)ws_size;
  gru_scan<<<4, 512, 0, stream>>>(
      (const float*)d_in[0],
      (const float*)d_in[1], (const float*)d_in[2],
      (const float*)d_in[3], (const float*)d_in[4],
      (const float*)d_in[5], (const float*)d_in[6],
      (const float*)d_in[7], (const float*)d_in[8],
      (float*)d_out);
}

// Round 3
// 7177.640 us; speedup vs baseline: 1.8305x; 1.8305x over previous
//
#include <hip/hip_runtime.h>

// GRU scan, 2 layers, B=64 T=4096 D=H=128 — layer-specialized waves.
// 4 persistent WGs x 16 batch rows x 512 threads (8 waves).
// Waves 0-3 compute layer 0, waves 4-7 compute layer 1 (skew 2 steps).
// Each wave owns 2 unit-groups (32 hidden units) of its layer: 96 weight
// frags (one layer only) stationary in VGPR/AGPR.
// Per step, per wave: P1 = 24 h-part MFMAs; P2 = gates + 24 input-part MFMAs.
// Fully uniform loop body: per-wave base pointers give L0: input=X buf,
// h=H0 buf; L1: input=H0 buf, h=H1 buf. All parities reduce to (t&1)/((t+1)&1).
// Schedule (sigma = step index of this wave's layer):
//   L0: sigma = t      input-MFMA(sigma) in P2(t-1), h-MFMA in P1(t), gates in P2(t)
//   L1: sigma = t - 2  (2-step skew gives h0' a full barrier of slack)
// LDS: 6 frag-linear blocks (X0 X1 H0a H0b H1a H1b), reads are lane*16
// contiguous (conflict-free m97 pattern).

#define Tlen 4096
#define Hd   128
#define Bsz  64

typedef __attribute__((ext_vector_type(8))) short short8;     // 8 bf16
typedef __attribute__((ext_vector_type(4))) short short4v;    // 4 bf16
typedef __attribute__((ext_vector_type(4))) float float4v;
typedef __attribute__((ext_vector_type(2))) unsigned int uint2v;

#define MFMA16(a, b, c) __builtin_amdgcn_mfma_f32_16x16x32_bf16((a), (b), (c), 0, 0, 0)

static __device__ __forceinline__ float fast_exp2(float x) {
#if __has_builtin(__builtin_amdgcn_exp2f)
  return __builtin_amdgcn_exp2f(x);
#else
  return exp2f(x);
#endif
}
static __device__ __forceinline__ float fast_rcp(float x) {
  return __builtin_amdgcn_rcpf(x);
}
static __device__ __forceinline__ short f2bf(float f) {  // RTNE fp32->bf16
  unsigned u = __builtin_bit_cast(unsigned, f);
  u = (u + 0x7FFFu + ((u >> 16) & 1u)) >> 16;
  return (short)u;
}
static __device__ __forceinline__ unsigned pk2bf(float a, float b) {  // lo=a hi=b
#if __has_builtin(__builtin_amdgcn_cvt_pk_bf16_f32)
  auto v = __builtin_amdgcn_cvt_pk_bf16_f32(a, b);
  return __builtin_bit_cast(unsigned, v);
#else
  return (unsigned)(unsigned short)f2bf(a) | ((unsigned)(unsigned short)f2bf(b) << 16);
#endif
}
static __device__ __forceinline__ short8 loadw8(const float* __restrict__ p) {
  short8 r;
  #pragma unroll
  for (int j = 0; j < 8; ++j) r[j] = f2bf(p[j]);
  return r;
}

// LDS blocks (short indices). Block = 4 ksteps x 64 lanes x 8 shorts = 2048.
// Frag-linear: addr(row, k) = (k>>5)*512 + ((k>>3)&3)*128 + row*8 + (k&7);
// reader lane l, kstep s does b128 at s*512 + l*8.
#define XB   0
#define H0B  4096
#define H1B  8192
#define BLK  2048

__global__ __launch_bounds__(512, 2) void gru_scan(
    const float* __restrict__ x,
    const float* __restrict__ Wih0, const float* __restrict__ Whh0,
    const float* __restrict__ bih0, const float* __restrict__ bhh0,
    const float* __restrict__ Wih1, const float* __restrict__ Whh1,
    const float* __restrict__ bih1, const float* __restrict__ bhh1,
    float* __restrict__ out) {
  __shared__ alignas(16) short Abuf[12288];  // 24 KB

  const int tid   = threadIdx.x;
  const int wave  = tid >> 6;
  const int lane  = tid & 63;
  const int lc    = lane & 15;
  const int quad  = lane >> 4;
  const int q8    = quad * 8;
  const int lane8 = lane * 8;
  const int bbase = blockIdx.x * 16;

  const int wgrp = wave >> 2;     // 0 = layer0 waves, 1 = layer1 waves
  const int w4   = wave & 3;

  const float* Wi = wgrp ? Wih1 : Wih0;
  const float* Wh = wgrp ? Whh1 : Whh0;
  const float* bi = wgrp ? bih1 : bih0;
  const float* bh = wgrp ? bhh1 : bhh0;

  // ---- stationary weight fragments: ONE layer, 2 unit-groups -------------
  short8 fxr[2][4], fxz[2][4], fxn[2][4];   // input-side (Wih)
  short8 fhr[2][4], fhz[2][4], fhn[2][4];   // hidden-side (Whh)
  float kr[2], kz[2], ki[2], kh[2];
  const float nL  = -1.44269504088896f;     // -log2(e)
  const float n2L = -2.88539008177793f;     // -2*log2(e)
  #pragma unroll
  for (int G = 0; G < 2; ++G) {
    const int c = 32 * w4 + 16 * G + lc;    // unit (column) this lane owns
    #pragma unroll
    for (int s = 0; s < 4; ++s) {
      const int k = 32 * s + q8;
      fxr[G][s] = loadw8(Wi + (c)       * Hd + k);
      fxz[G][s] = loadw8(Wi + (128 + c) * Hd + k);
      fxn[G][s] = loadw8(Wi + (256 + c) * Hd + k);
      fhr[G][s] = loadw8(Wh + (c)       * Hd + k);
      fhz[G][s] = loadw8(Wh + (128 + c) * Hd + k);
      fhn[G][s] = loadw8(Wh + (256 + c) * Hd + k);
    }
    kr[G] = nL  * (bi[c] + bh[c]);
    kz[G] = nL  * (bi[128 + c] + bh[128 + c]);
    ki[G] = n2L * bi[256 + c];
    kh[G] = n2L * bh[256 + c];
  }

  // LDS bases per wave-group
  const int hsel = wgrp ? H1B : H0B;   // h-part read (P1) + h write (P2)
  const int isel = wgrp ? H0B : XB;    // input-part read (P2)

  // h-write offsets (frag layout, k = unit): u>>5 == w4 for our groups
  int hw[2];
  #pragma unroll
  for (int G = 0; G < 2; ++G)
    hw[G] = w4 * 512 + (2 * G + (lc >> 3)) * 128 + (lc & 7);

  // x staging slots: thread -> (row, k0..k0+3)
  const int xrow = tid >> 5;
  const int xk0  = 4 * (tid & 31);
  const int xwoff = (xk0 >> 5) * 512 + ((xk0 >> 3) & 3) * 128 + xrow * 8 + (xk0 & 7);
  const float* xg = x + (size_t)(bbase + xrow) * (Tlen * Hd) + xk0;

  // gate-validity window: L0 steps t in [0,T), L1 sigma=t-2 -> t in [2,T+2)
  const int glo = wgrp ? 2 : 0;
  const int ghi = glo + Tlen;

  // ---- prologue ----------------------------------------------------------
  {
    int* zb = (int*)Abuf;               // zero H0/H1 blocks: dwords [2048,6144)
    #pragma unroll
    for (int i = 0; i < 8; ++i) zb[2048 + tid + 512 * i] = 0;
    const float4v v0 = *(const float4v*)(xg);                 // x(0)
    const float4v v1 = *(const float4v*)(xg + Hd);            // x(1)
    uint2v p0 = {pk2bf(v0[0], v0[1]), pk2bf(v0[2], v0[3])};
    uint2v p1 = {pk2bf(v1[0], v1[1]), pk2bf(v1[2], v1[3])};
    *(short4v*)&Abuf[XB + xwoff]       = __builtin_bit_cast(short4v, p0);
    *(short4v*)&Abuf[XB + BLK + xwoff] = __builtin_bit_cast(short4v, p1);
  }
  __syncthreads();

  const float4v Z4 = {0.f, 0.f, 0.f, 0.f};
  float4v ar[2], az[2], an[2], ah[2];
  float4v hp[2] = {Z4, Z4};

  // prologue "P2(-1)": input-part MFMAs (L0: x(0) from X[0]; L1: zeros)
  #pragma unroll
  for (int G = 0; G < 2; ++G) { ar[G] = Z4; az[G] = Z4; an[G] = Z4; ah[G] = Z4; }
  #pragma unroll
  for (int s = 0; s < 4; ++s) {
    const short8 a = *(const short8*)&Abuf[isel + s * 512 + lane8];
    #pragma unroll
    for (int G = 0; G < 2; ++G) {
      ar[G] = MFMA16(a, fxr[G][s], ar[G]);
      az[G] = MFMA16(a, fxz[G][s], az[G]);
      an[G] = MFMA16(a, fxn[G][s], an[G]);
    }
  }

  // ---- main loop: T+2 iterations (2-step drain for layer 1) --------------
  for (int t = 0; t < Tlen + 2; ++t) {
    const int par  = (t & 1) * BLK;     // parity t block offset
    const int parx = BLK - par;         // parity (t+1) block offset

    // ---- P1: h-part MFMAs (24) + x(t+2) global prefetch ----
    const int tn = (t + 2 < Tlen) ? (t + 2) : (Tlen - 1);
    const float4v xv = *(const float4v*)(xg + (size_t)tn * Hd);
    const int hrd = hsel + parx;
    #pragma unroll
    for (int s = 0; s < 4; ++s) {
      const short8 a = *(const short8*)&Abuf[hrd + s * 512 + lane8];
      #pragma unroll
      for (int G = 0; G < 2; ++G) {
        ar[G] = MFMA16(a, fhr[G][s], ar[G]);
        az[G] = MFMA16(a, fhz[G][s], az[G]);
        ah[G] = MFMA16(a, fhn[G][s], ah[G]);
      }
    }
    __syncthreads();

    // ---- P2: gates (consume accs) + h write + x stage + input MFMAs ----
    if (t >= glo && t < ghi) {
      const int wr = hsel + par;
      #pragma unroll
      for (int G = 0; G < 2; ++G) {
        #pragma unroll
        for (int i = 0; i < 4; ++i) {
          const float er = fast_exp2(fmaf(ar[G][i], nL, kr[G]));
          const float rr = fast_rcp(1.0f + er);
          const float ez = fast_exp2(fmaf(az[G][i], nL, kz[G]));
          const float zz = fast_rcp(1.0f + ez);
          float vv = fmaf(rr, fmaf(ah[G][i], n2L, kh[G]),
                          fmaf(an[G][i], n2L, ki[G]));
          vv = fminf(vv, 126.0f);
          const float e2 = fast_exp2(vv);
          const float nn = (1.0f - e2) * fast_rcp(1.0f + e2);
          const float hn = fmaf(zz, hp[G][i] - nn, nn);
          hp[G][i] = hn;
          Abuf[wr + hw[G] + (quad * 4 + i) * 8] = f2bf(hn);
        }
      }
    }
    {  // stage x(t+2) into X[t&1] (dead buffer; consumed in P2(t+2))
      uint2v pp = {pk2bf(xv[0], xv[1]), pk2bf(xv[2], xv[3])};
      *(short4v*)&Abuf[XB + par + xwoff] = __builtin_bit_cast(short4v, pp);
    }
    // input-part MFMAs for next step (re-init accs)
    const int ird = isel + parx;
    #pragma unroll
    for (int G = 0; G < 2; ++G) { ar[G] = Z4; az[G] = Z4; an[G] = Z4; ah[G] = Z4; }
    #pragma unroll
    for (int s = 0; s < 4; ++s) {
      const short8 a = *(const short8*)&Abuf[ird + s * 512 + lane8];
      #pragma unroll
      for (int G = 0; G < 2; ++G) {
        ar[G] = MFMA16(a, fxr[G][s], ar[G]);
        az[G] = MFMA16(a, fxz[G][s], az[G]);
        an[G] = MFMA16(a, fxn[G][s], an[G]);
      }
    }
    __syncthreads();
  }

  // ---- output: L0 waves hold h0(T-1), L1 waves hold h1(T-1) --------------
  #pragma unroll
  for (int G = 0; G < 2; ++G) {
    const int u = 32 * w4 + 16 * G + lc;
    #pragma unroll
    for (int i = 0; i < 4; ++i) {
      const int b = bbase + quad * 4 + i;
      out[wgrp * (Bsz * Hd) + b * Hd + u] = hp[G][i];
    }
  }
}

extern "C" void kernel_launch(void* const* d_in, const int* in_sizes, int n_in,
                              void* d_out, int out_size, void* d_ws, size_t ws_size,
                              hipStream_t stream) {
  (void)in_sizes; (void)n_in; (void)out_size; (void)d_ws; (void)ws_size;
  gru_scan<<<4, 512, 0, stream>>>(
      (const float*)d_in[0],
      (const float*)d_in[1], (const float*)d_in[2],
      (const float*)d_in[3], (const float*)d_in[4],
      (const float*)d_in[5], (const float*)d_in[6],
      (const float*)d_in[7], (const float*)d_in[8],
      (float*)d_out);
}